// Round 4
// baseline (2520.649 us; speedup 1.0000x reference)
//
#include <hip/hip_runtime.h>

#define HID 256
#define T_STEPS 1024
#define F_IN 40
#define NSPK 1251
#define NCHUNK 16            // blocks per layer, 16 h-values each
#define NBLOCKS (3 * NCHUNK)
#define K2_THREADS 512

// workspace layout (bytes):
//   hbuf : u64 [3][1025][256] tagged exchange words (tag<<32 | f32 bits)
#define HBUF_BYTES ((size_t)3 * 1025 * 256 * 8)
//   xg   : f32 [1024][1024]  layer-0 input projection (no bias)
#define XG_OFF     HBUF_BYTES
#define XG_BYTES   ((size_t)1024 * 1024 * 4)
//   h2f  : f32 [1024][256]   layer-2 h for the logits GEMM
#define H2F_OFF    (XG_OFF + XG_BYTES)

__device__ __forceinline__ float fast_sig(float v) {
    return __builtin_amdgcn_rcpf(1.f + __expf(-v));
}
__device__ __forceinline__ float fast_tanh(float v) {
    return 2.f * __builtin_amdgcn_rcpf(1.f + __expf(-2.f * v)) - 1.f;
}
__device__ __forceinline__ float d4f(float4 a, float4 b) {
    return a.x * b.x + a.y * b.y + a.z * b.z + a.w * b.w;
}
__device__ __forceinline__ float wait_tag(const unsigned long long* p, unsigned want) {
    unsigned long long v;
    do {
        v = __hip_atomic_load(p, __ATOMIC_RELAXED, __HIP_MEMORY_SCOPE_AGENT);
    } while ((unsigned)(v >> 32) != want);
    return __uint_as_float((unsigned)v);
}

// ---------------- K0: init tags for t=0 ----------------
__global__ void k0_init(unsigned long long* __restrict__ hbuf) {
    int tid = threadIdx.x;
    if (tid < 3 * HID) {
        int l = tid / HID, k = tid % HID;
        hbuf[(size_t)(l * 1025 + 0) * HID + k] = 0ull;   // tag 0, value 0.0f
    }
}

// ---------------- K1: xg[t][r] = sum_k w_ih0[r][k] * x[63][t][k] ----------------
__global__ __launch_bounds__(256) void k1_xproj(const float* __restrict__ x,
                                                const float* __restrict__ w_ih0,
                                                float* __restrict__ xg) {
    __shared__ float xs[8][F_IN];
    int b = blockIdx.x, tid = threadIdx.x;
    const float* x63 = x + (size_t)63 * T_STEPS * F_IN + (size_t)b * 8 * F_IN;
    for (int i = tid; i < 8 * F_IN; i += 256) xs[i / F_IN][i % F_IN] = x63[i];
    __syncthreads();
    for (int rr = 0; rr < 4; rr++) {
        int r = tid + rr * 256;
        float wrow[F_IN];
        #pragma unroll
        for (int k = 0; k < F_IN; k++) wrow[k] = w_ih0[r * F_IN + k];
        #pragma unroll
        for (int tt = 0; tt < 8; tt++) {
            float a = 0.f;
            #pragma unroll
            for (int k = 0; k < F_IN; k++) a += wrow[k] * xs[tt][k];
            xg[(size_t)(b * 8 + tt) * 1024 + r] = a;
        }
    }
}

// ---------------- K2: pipelined 3-layer LSTM, register-resident weights ----------------
__global__ __launch_bounds__(K2_THREADS, 2) void k2_lstm(
    const float* __restrict__ w_ih1, const float* __restrict__ w_hh0,
    const float* __restrict__ b_ih0, const float* __restrict__ b_hh0,
    const float* __restrict__ w_hh1,
    const float* __restrict__ b_ih1, const float* __restrict__ b_hh1,
    const float* __restrict__ w_ih2, const float* __restrict__ w_hh2,
    const float* __restrict__ b_ih2, const float* __restrict__ b_hh2,
    const float* __restrict__ xg,
    unsigned long long* __restrict__ hbuf, float* __restrict__ h2f)
{
    const int bid   = blockIdx.x;
    const int layer = bid / NCHUNK;
    const int g     = bid % NCHUNK;
    const int tid   = threadIdx.x;
    const int lane  = tid & 63;
    const int wv    = tid >> 6;          // wave 0..7
    const int seg   = lane & 7;          // k-segment 0..7
    const int jj    = (lane >> 3) & 1;   // 0..1
    const int q     = lane >> 4;         // gate 0..3 (i,f,g,o)
    const int j     = g * 16 + wv * 2 + jj;   // h index 0..255
    const int r     = q * 256 + j;            // gate row 0..1023

    const float* wih = (layer == 1) ? w_ih1 : w_ih2;
    const float* whh = (layer == 0) ? w_hh0 : (layer == 1) ? w_hh1 : w_hh2;
    const float* bih = (layer == 0) ? b_ih0 : (layer == 1) ? b_ih1 : b_ih2;
    const float* bhh = (layer == 0) ? b_hh0 : (layer == 1) ? b_hh1 : b_hh2;
    const float bias = bih[r] + bhh[r];

    // LDS: own-h double buffer + prev-h quadruple buffer (WAR-safe w/ 1 barrier/step)
    __shared__ float ownb[2][256];
    __shared__ float prevb[4][256];

    // ---- weights as NAMED float4 SSA values (no alloca -> guaranteed VGPRs) ----
    // layer 0: 8 float4 over own-h K=256 (xg covers the input half)
    // layers 1,2: seg<4 -> w_ih slice, seg>=4 -> w_hh slice; 16 float4 (K=64)
    // rotation by 'seg' float4s makes the LDS dot reads bank-conflict-free.
    float4 w0, w1, w2, w3, w4, w5, w6, w7, w8, w9, w10, w11, w12, w13, w14, w15;
    if (layer == 0) {
        const float4* s4 = (const float4*)(whh + (size_t)r * HID + seg * 32);
        w0 = s4[(0 + seg) & 7]; w1 = s4[(1 + seg) & 7];
        w2 = s4[(2 + seg) & 7]; w3 = s4[(3 + seg) & 7];
        w4 = s4[(4 + seg) & 7]; w5 = s4[(5 + seg) & 7];
        w6 = s4[(6 + seg) & 7]; w7 = s4[(7 + seg) & 7];
        w8 = w9 = w10 = w11 = w12 = w13 = w14 = w15 = make_float4(0.f, 0.f, 0.f, 0.f);
    } else {
        const float* base = (seg < 4) ? (wih + (size_t)r * HID + seg * 64)
                                      : (whh + (size_t)r * HID + (seg - 4) * 64);
        const float4* s4 = (const float4*)base;
        w0  = s4[(0 + seg) & 15];  w1  = s4[(1 + seg) & 15];
        w2  = s4[(2 + seg) & 15];  w3  = s4[(3 + seg) & 15];
        w4  = s4[(4 + seg) & 15];  w5  = s4[(5 + seg) & 15];
        w6  = s4[(6 + seg) & 15];  w7  = s4[(7 + seg) & 15];
        w8  = s4[(8 + seg) & 15];  w9  = s4[(9 + seg) & 15];
        w10 = s4[(10 + seg) & 15]; w11 = s4[(11 + seg) & 15];
        w12 = s4[(12 + seg) & 15]; w13 = s4[(13 + seg) & 15];
        w14 = s4[(14 + seg) & 15]; w15 = s4[(15 + seg) & 15];
    }

    unsigned long long* h_own = hbuf + (size_t)layer * 1025 * HID;
    const unsigned long long* h_prev =
        (layer > 0) ? (hbuf + (size_t)(layer - 1) * 1025 * HID) : h_own;

    // pre-fill prevb[0] with prev-layer h tag 1 (consumed at t=0)
    if (layer > 0 && tid >= 256) {
        int kx = tid - 256;
        prevb[0][kx] = wait_tag(h_prev + (size_t)1 * HID + kx, 1u);
    }
    __syncthreads();

    float c_state = 0.f;   // valid in lanes with (lane&55)==0

    for (int t = 0; t < T_STEPS; t++) {
        // early-issue xg load (used after the dot)
        float xgv = 0.f;
        if (layer == 0 && seg == 0) xgv = xg[(size_t)t * 1024 + r];

        // ---- polls ----
        if (tid < 256) {
            // own-layer h[t] (tag t) -> ownb[t&1]
            ownb[t & 1][tid] = wait_tag(h_own + (size_t)t * HID + tid, (unsigned)t);
        } else if (layer > 0 && t + 2 <= T_STEPS) {
            // prefetch prev-layer h tag t+2 -> prevb[(t+1)&3]
            int kx = tid - 256;
            prevb[(t + 1) & 3][kx] =
                wait_tag(h_prev + (size_t)(t + 2) * HID + kx, (unsigned)(t + 2));
        }
        __syncthreads();

        // ---- dot (weights in VGPRs, broadcast LDS reads, seg-rotated) ----
        float acc;
        if (layer == 0) {
            const float4* i4 = (const float4*)(&ownb[t & 1][seg * 32]);
            acc  = d4f(w0, i4[(0 + seg) & 7]);
            acc += d4f(w1, i4[(1 + seg) & 7]);
            acc += d4f(w2, i4[(2 + seg) & 7]);
            acc += d4f(w3, i4[(3 + seg) & 7]);
            acc += d4f(w4, i4[(4 + seg) & 7]);
            acc += d4f(w5, i4[(5 + seg) & 7]);
            acc += d4f(w6, i4[(6 + seg) & 7]);
            acc += d4f(w7, i4[(7 + seg) & 7]);
        } else {
            const float4* i4 = (seg < 4)
                ? (const float4*)(&prevb[t & 3][seg * 64])
                : (const float4*)(&ownb[t & 1][(seg - 4) * 64]);
            acc  = d4f(w0,  i4[(0 + seg) & 15]);
            acc += d4f(w1,  i4[(1 + seg) & 15]);
            acc += d4f(w2,  i4[(2 + seg) & 15]);
            acc += d4f(w3,  i4[(3 + seg) & 15]);
            acc += d4f(w4,  i4[(4 + seg) & 15]);
            acc += d4f(w5,  i4[(5 + seg) & 15]);
            acc += d4f(w6,  i4[(6 + seg) & 15]);
            acc += d4f(w7,  i4[(7 + seg) & 15]);
            acc += d4f(w8,  i4[(8 + seg) & 15]);
            acc += d4f(w9,  i4[(9 + seg) & 15]);
            acc += d4f(w10, i4[(10 + seg) & 15]);
            acc += d4f(w11, i4[(11 + seg) & 15]);
            acc += d4f(w12, i4[(12 + seg) & 15]);
            acc += d4f(w13, i4[(13 + seg) & 15]);
            acc += d4f(w14, i4[(14 + seg) & 15]);
            acc += d4f(w15, i4[(15 + seg) & 15]);
        }

        // ---- seg reduction (butterfly over lane bits 0..2) ----
        acc += __shfl_xor(acc, 1, 64);
        acc += __shfl_xor(acc, 2, 64);
        acc += __shfl_xor(acc, 4, 64);
        // only seg==0 lanes carry bias(+xg); gathers below only read seg==0 lanes
        float gtot = acc + ((seg == 0) ? (bias + xgv) : 0.f);

        // ---- gate gather across q (lane bits 4,5) ----
        float gI = gtot;
        float gF = __shfl_xor(gtot, 16, 64);
        float gG = __shfl_xor(gtot, 32, 64);
        float gO = __shfl_xor(gtot, 48, 64);

        // ---- state update + publish: lanes with q==0 && seg==0 (lane 0, 8) ----
        if ((lane & 55) == 0) {
            float si = fast_sig(gI);
            float sf = fast_sig(gF);
            float so = fast_sig(gO);
            c_state = sf * c_state + si * fast_tanh(gG);
            float hv = so * fast_tanh(c_state);
            unsigned long long word =
                ((unsigned long long)(unsigned)(t + 1) << 32) |
                (unsigned long long)__float_as_uint(hv);
            __hip_atomic_store(h_own + (size_t)(t + 1) * HID + j, word,
                               __ATOMIC_RELAXED, __HIP_MEMORY_SCOPE_AGENT);
            if (layer == 2) h2f[(size_t)t * HID + j] = hv;
        }
        // single barrier per step (buffer rotation makes next-step writes WAR-safe)
    }
}

// ---------------- K3: logits = h2 @ w_lin^T + b_lin ----------------
#define BM 64
#define BN 64
#define BK 32
__global__ __launch_bounds__(256) void k3_logits(
    const float* __restrict__ A, const float* __restrict__ w_lin,
    const float* __restrict__ b_lin, float* __restrict__ out)
{
    int m0 = blockIdx.x * BM;
    int n0 = blockIdx.y * BN;
    int tid = threadIdx.x;
    __shared__ float As[BM][BK + 1];
    __shared__ float Bs[BN][BK + 1];
    float accv[4][4] = {};
    int tx = tid % 16, ty = tid / 16;

    for (int k0 = 0; k0 < HID; k0 += BK) {
        int row = tid / 4;
        int kq  = (tid % 4) * 8;
        {
            const float4* src = (const float4*)(A + (size_t)(m0 + row) * HID + k0 + kq);
            float4 v0 = src[0], v1 = src[1];
            As[row][kq + 0] = v0.x; As[row][kq + 1] = v0.y; As[row][kq + 2] = v0.z; As[row][kq + 3] = v0.w;
            As[row][kq + 4] = v1.x; As[row][kq + 5] = v1.y; As[row][kq + 6] = v1.z; As[row][kq + 7] = v1.w;
        }
        {
            int n = n0 + row;
            float4 v0 = make_float4(0.f, 0.f, 0.f, 0.f), v1 = v0;
            if (n < NSPK) {
                const float4* src = (const float4*)(w_lin + (size_t)n * HID + k0 + kq);
                v0 = src[0]; v1 = src[1];
            }
            Bs[row][kq + 0] = v0.x; Bs[row][kq + 1] = v0.y; Bs[row][kq + 2] = v0.z; Bs[row][kq + 3] = v0.w;
            Bs[row][kq + 4] = v1.x; Bs[row][kq + 5] = v1.y; Bs[row][kq + 6] = v1.z; Bs[row][kq + 7] = v1.w;
        }
        __syncthreads();
        #pragma unroll
        for (int kk = 0; kk < BK; kk++) {
            float a0 = As[ty * 4 + 0][kk], a1 = As[ty * 4 + 1][kk];
            float a2 = As[ty * 4 + 2][kk], a3 = As[ty * 4 + 3][kk];
            float b0 = Bs[tx * 4 + 0][kk], b1 = Bs[tx * 4 + 1][kk];
            float b2 = Bs[tx * 4 + 2][kk], b3 = Bs[tx * 4 + 3][kk];
            accv[0][0] += a0 * b0; accv[0][1] += a0 * b1; accv[0][2] += a0 * b2; accv[0][3] += a0 * b3;
            accv[1][0] += a1 * b0; accv[1][1] += a1 * b1; accv[1][2] += a1 * b2; accv[1][3] += a1 * b3;
            accv[2][0] += a2 * b0; accv[2][1] += a2 * b1; accv[2][2] += a2 * b2; accv[2][3] += a2 * b3;
            accv[3][0] += a3 * b0; accv[3][1] += a3 * b1; accv[3][2] += a3 * b2; accv[3][3] += a3 * b3;
        }
        __syncthreads();
    }
    #pragma unroll
    for (int i = 0; i < 4; i++) {
        int m = m0 + ty * 4 + i;
        #pragma unroll
        for (int j2 = 0; j2 < 4; j2++) {
            int n = n0 + tx * 4 + j2;
            if (n < NSPK) out[(size_t)m * NSPK + n] = accv[i][j2] + b_lin[n];
        }
    }
}

// ---------------- K4: in-place row-wise log_softmax ----------------
__global__ __launch_bounds__(256) void k4_logsoftmax(float* __restrict__ out)
{
    int t = blockIdx.x;
    float* row = out + (size_t)t * NSPK;
    int tid = threadIdx.x;
    __shared__ float red[8];
    float vals[5];
    float lmax = -1e30f;
    #pragma unroll
    for (int k = 0; k < 5; k++) {
        int n = tid + k * 256;
        vals[k] = (n < NSPK) ? row[n] : -1e30f;
        lmax = fmaxf(lmax, vals[k]);
    }
    #pragma unroll
    for (int m = 1; m < 64; m <<= 1) lmax = fmaxf(lmax, __shfl_xor(lmax, m, 64));
    int wave = tid >> 6;
    if ((tid & 63) == 0) red[wave] = lmax;
    __syncthreads();
    float gmax = fmaxf(fmaxf(red[0], red[1]), fmaxf(red[2], red[3]));
    float lsum = 0.f;
    #pragma unroll
    for (int k = 0; k < 5; k++) {
        int n = tid + k * 256;
        if (n < NSPK) lsum += __expf(vals[k] - gmax);
    }
    #pragma unroll
    for (int m = 1; m < 64; m <<= 1) lsum += __shfl_xor(lsum, m, 64);
    if ((tid & 63) == 0) red[4 + wave] = lsum;
    __syncthreads();
    float lse = logf(red[4] + red[5] + red[6] + red[7]) + gmax;
    #pragma unroll
    for (int k = 0; k < 5; k++) {
        int n = tid + k * 256;
        if (n < NSPK) row[n] = vals[k] - lse;
    }
}

extern "C" void kernel_launch(void* const* d_in, const int* in_sizes, int n_in,
                              void* d_out, int out_size, void* d_ws, size_t ws_size,
                              hipStream_t stream) {
    const float* x     = (const float*)d_in[0];
    const float* w_ih0 = (const float*)d_in[1];
    const float* w_hh0 = (const float*)d_in[2];
    const float* b_ih0 = (const float*)d_in[3];
    const float* b_hh0 = (const float*)d_in[4];
    const float* w_ih1 = (const float*)d_in[5];
    const float* w_hh1 = (const float*)d_in[6];
    const float* b_ih1 = (const float*)d_in[7];
    const float* b_hh1 = (const float*)d_in[8];
    const float* w_ih2 = (const float*)d_in[9];
    const float* w_hh2 = (const float*)d_in[10];
    const float* b_ih2 = (const float*)d_in[11];
    const float* b_hh2 = (const float*)d_in[12];
    const float* w_lin = (const float*)d_in[13];
    const float* b_lin = (const float*)d_in[14];

    unsigned long long* hbuf = (unsigned long long*)d_ws;
    float* xg  = (float*)((char*)d_ws + XG_OFF);
    float* h2f = (float*)((char*)d_ws + H2F_OFF);
    float* out = (float*)d_out;

    k0_init<<<1, 1024, 0, stream>>>(hbuf);
    k1_xproj<<<128, 256, 0, stream>>>(x, w_ih0, xg);
    k2_lstm<<<NBLOCKS, K2_THREADS, 0, stream>>>(
        w_ih1, w_hh0, b_ih0, b_hh0,
        w_hh1, b_ih1, b_hh1,
        w_ih2, w_hh2, b_ih2, b_hh2,
        xg, hbuf, h2f);
    k3_logits<<<dim3(16, 20), 256, 0, stream>>>(h2f, w_lin, b_lin, out);
    k4_logsoftmax<<<T_STEPS, 256, 0, stream>>>(out);
}

// Round 6
// 2514.979 us; speedup vs baseline: 1.0023x; 1.0023x over previous
//
#include <hip/hip_runtime.h>

#define HID 256
#define T_STEPS 1024
#define F_IN 40
#define NSPK 1251
#define NCHUNK 8             // blocks per layer, 32 h-values each
#define NBLOCKS (3 * NCHUNK)
#define K2_THREADS 512

// workspace layout (bytes):
//   hbuf : u64 [3][1025][256] tagged exchange words (tag<<32 | f32 bits)
#define HBUF_BYTES ((size_t)3 * 1025 * 256 * 8)
//   xg   : f32 [1024][1024]  layer-0 input projection (no bias)
#define XG_OFF     HBUF_BYTES
#define XG_BYTES   ((size_t)1024 * 1024 * 4)
//   h2f  : f32 [1024][256]   layer-2 h for the logits GEMM
#define H2F_OFF    (XG_OFF + XG_BYTES)

// LDS layout (floats), padded stride 264 = 256 + 8 (pad at half point) so the
// 4 k-segments' base banks are distinct-or-2-way (2-way is free on gfx950):
//   prevb buffers 0..3 at 0,264,528,792 ; ownb buffers 0..1 at 1056,1320
#define PBSTRIDE 264
#define OWN_BASE (4 * PBSTRIDE)
#define SMEM_FLOATS (6 * PBSTRIDE)

__device__ __forceinline__ float fast_sig(float v) {
    return __builtin_amdgcn_rcpf(1.f + __expf(-v));
}
__device__ __forceinline__ float fast_tanh(float v) {
    return 2.f * __builtin_amdgcn_rcpf(1.f + __expf(-2.f * v)) - 1.f;
}
__device__ __forceinline__ float d4f(float4 a, float4 b) {
    return a.x * b.x + a.y * b.y + a.z * b.z + a.w * b.w;
}
__device__ __forceinline__ float wait_tag(const unsigned long long* p, unsigned want) {
    unsigned long long v;
    do {
        v = __hip_atomic_load(p, __ATOMIC_RELAXED, __HIP_MEMORY_SCOPE_AGENT);
    } while ((unsigned)(v >> 32) != want);
    return __uint_as_float((unsigned)v);
}

// ---------------- K0: init tags for t=0 ----------------
__global__ void k0_init(unsigned long long* __restrict__ hbuf) {
    int tid = threadIdx.x;
    if (tid < 3 * HID) {
        int l = tid / HID, k = tid % HID;
        hbuf[(size_t)(l * 1025 + 0) * HID + k] = 0ull;   // tag 0, value 0.0f
    }
}

// ---------------- K1: xg[t][r] = sum_k w_ih0[r][k] * x[63][t][k] ----------------
__global__ __launch_bounds__(256) void k1_xproj(const float* __restrict__ x,
                                                const float* __restrict__ w_ih0,
                                                float* __restrict__ xg) {
    __shared__ float xs[8][F_IN];
    int b = blockIdx.x, tid = threadIdx.x;
    const float* x63 = x + (size_t)63 * T_STEPS * F_IN + (size_t)b * 8 * F_IN;
    for (int i = tid; i < 8 * F_IN; i += 256) xs[i / F_IN][i % F_IN] = x63[i];
    __syncthreads();
    for (int rr = 0; rr < 4; rr++) {
        int r = tid + rr * 256;
        float wrow[F_IN];
        #pragma unroll
        for (int k = 0; k < F_IN; k++) wrow[k] = w_ih0[r * F_IN + k];
        #pragma unroll
        for (int tt = 0; tt < 8; tt++) {
            float a = 0.f;
            #pragma unroll
            for (int k = 0; k < F_IN; k++) a += wrow[k] * xs[tt][k];
            xg[(size_t)(b * 8 + tt) * 1024 + r] = a;
        }
    }
}

// ---------------- K2: pipelined 3-layer LSTM, asm-loaded register weights ----------------
// lane layout: bits[1:0]=seg(K-quarter), bits[3:2]=q(gate), bits[5:4]=j-sub; jl = wv*4+(lane>>4)
__global__ __launch_bounds__(K2_THREADS, 2) void k2_lstm(
    const float* __restrict__ w_ih1, const float* __restrict__ w_hh0,
    const float* __restrict__ b_ih0, const float* __restrict__ b_hh0,
    const float* __restrict__ w_hh1,
    const float* __restrict__ b_ih1, const float* __restrict__ b_hh1,
    const float* __restrict__ w_ih2, const float* __restrict__ w_hh2,
    const float* __restrict__ b_ih2, const float* __restrict__ b_hh2,
    const float* __restrict__ xg,
    unsigned long long* __restrict__ hbuf, float* __restrict__ h2f)
{
    const int bid   = blockIdx.x;
    const int layer = bid / NCHUNK;
    const int g     = bid % NCHUNK;
    const int tid   = threadIdx.x;
    const int lane  = tid & 63;
    const int wv    = tid >> 6;              // wave 0..7
    const int seg   = lane & 3;              // K-quarter: 0,1 = ih(prev-h), 2,3 = hh(own-h)
    const int q     = (lane >> 2) & 3;       // gate 0..3 (i,f,g,o)
    const int jl    = wv * 4 + (lane >> 4);  // local h index 0..31
    const int jg    = g * 32 + jl;           // global h index 0..255
    const int r     = q * 256 + jg;          // gate row 0..1023

    const float* wih = (layer == 1) ? w_ih1 : w_ih2;   // layer0: ih half zero (xg covers it)
    const float* whh = (layer == 0) ? w_hh0 : (layer == 1) ? w_hh1 : w_hh2;
    const float* bih = (layer == 0) ? b_ih0 : (layer == 1) ? b_ih1 : b_ih2;
    const float* bhh = (layer == 0) ? b_hh0 : (layer == 1) ? b_hh1 : b_hh2;
    const float bias = bih[r] + bhh[r];

    __shared__ float smem[SMEM_FLOATS];

    // ---- 32 float4 weights per thread, loaded via opaque asm (cannot be
    //      rematerialized/re-loaded: register file is their only legal home) ----
    float4 w0,w1,w2,w3,w4,w5,w6,w7,w8,w9,w10,w11,w12,w13,w14,w15,
           w16,w17,w18,w19,w20,w21,w22,w23,w24,w25,w26,w27,w28,w29,w30,w31;
    if (layer == 0 && seg < 2) {
        const float4 z = make_float4(0.f, 0.f, 0.f, 0.f);
        w0=w1=w2=w3=w4=w5=w6=w7=w8=w9=w10=w11=w12=w13=w14=w15=z;
        w16=w17=w18=w19=w20=w21=w22=w23=w24=w25=w26=w27=w28=w29=w30=w31=z;
    } else {
        const float* wbase = ((seg < 2) ? wih : whh) + (size_t)r * HID + (seg & 1) * 128;
#define LD8(P, A,B,C,D,E,F,G,H)                                               \
        asm volatile(                                                         \
            "global_load_dwordx4 %0, %8, off\n\t"                             \
            "global_load_dwordx4 %1, %8, off offset:16\n\t"                   \
            "global_load_dwordx4 %2, %8, off offset:32\n\t"                   \
            "global_load_dwordx4 %3, %8, off offset:48\n\t"                   \
            "global_load_dwordx4 %4, %8, off offset:64\n\t"                   \
            "global_load_dwordx4 %5, %8, off offset:80\n\t"                   \
            "global_load_dwordx4 %6, %8, off offset:96\n\t"                   \
            "global_load_dwordx4 %7, %8, off offset:112\n\t"                  \
            "s_waitcnt vmcnt(0)"                                              \
            : "=v"(A),"=v"(B),"=v"(C),"=v"(D),"=v"(E),"=v"(F),"=v"(G),"=v"(H) \
            : "v"(P) : "memory")
        LD8(wbase,      w0,w1,w2,w3,w4,w5,w6,w7);
        LD8(wbase + 32, w8,w9,w10,w11,w12,w13,w14,w15);
        LD8(wbase + 64, w16,w17,w18,w19,w20,w21,w22,w23);
        LD8(wbase + 96, w24,w25,w26,w27,w28,w29,w30,w31);
#undef LD8
    }

    for (int i = tid; i < SMEM_FLOATS; i += K2_THREADS) smem[i] = 0.f;
    __syncthreads();

    unsigned long long* h_own = hbuf + (size_t)layer * 1025 * HID;
    const unsigned long long* h_prev =
        (layer > 0) ? (hbuf + (size_t)(layer - 1) * 1025 * HID) : h_own;

    // pre-fill prevb[0] with prev-layer tag 1 (consumed at t=0)
    if (layer > 0 && tid >= 256) {
        int kx = tid - 256;
        smem[0 * PBSTRIDE + kx + 8 * (kx >> 7)] =
            wait_tag(h_prev + (size_t)1 * HID + kx, 1u);
    }
    __syncthreads();

    float c_state = 0.f;   // valid in lanes with (lane&15)==0

    for (int t = 0; t < T_STEPS; t++) {
        // early-issue xg load (used after the dot)
        float xgv = 0.f;
        if (layer == 0 && seg == 0) xgv = xg[(size_t)t * 1024 + r];

        // ---- poll phase ----
        if (tid < 256) {
            // own-layer h[t] (tag t) -> ownb[t&1]
            smem[OWN_BASE + (t & 1) * PBSTRIDE + tid + 8 * (tid >> 7)] =
                wait_tag(h_own + (size_t)t * HID + tid, (unsigned)t);
        } else if (layer > 0 && t + 2 <= T_STEPS) {
            // prefetch prev-layer tag t+2 -> prevb[(t+1)&3]
            int kx = tid - 256;
            smem[((t + 1) & 3) * PBSTRIDE + kx + 8 * (kx >> 7)] =
                wait_tag(h_prev + (size_t)(t + 2) * HID + kx, (unsigned)(t + 2));
        }
        __syncthreads();   // single barrier per step (buffer rotation gives WAR safety)

        // ---- dot: 32 asm-pinned float4s vs LDS window (padded layout, no conflicts) ----
        const float* inb = (seg < 2)
            ? &smem[(t & 3) * PBSTRIDE + (seg & 1) * 136]
            : &smem[OWN_BASE + (t & 1) * PBSTRIDE + (seg & 1) * 136];
        const float4* i4 = (const float4*)inb;
        float acc;
#define DOTW(i) d4f(w##i, i4[i])
        acc  = DOTW(0);  acc += DOTW(1);  acc += DOTW(2);  acc += DOTW(3);
        acc += DOTW(4);  acc += DOTW(5);  acc += DOTW(6);  acc += DOTW(7);
        acc += DOTW(8);  acc += DOTW(9);  acc += DOTW(10); acc += DOTW(11);
        acc += DOTW(12); acc += DOTW(13); acc += DOTW(14); acc += DOTW(15);
        acc += DOTW(16); acc += DOTW(17); acc += DOTW(18); acc += DOTW(19);
        acc += DOTW(20); acc += DOTW(21); acc += DOTW(22); acc += DOTW(23);
        acc += DOTW(24); acc += DOTW(25); acc += DOTW(26); acc += DOTW(27);
        acc += DOTW(28); acc += DOTW(29); acc += DOTW(30); acc += DOTW(31);
#undef DOTW

        // ---- seg reduction (lane bits 0,1) ----
        acc += __shfl_xor(acc, 1, 64);
        acc += __shfl_xor(acc, 2, 64);
        float gtot = acc + ((seg == 0) ? (bias + xgv) : 0.f);

        // ---- gate gather across q (lane bits 2,3); valid on (lane&15)==0 ----
        float gI = gtot;
        float gF = __shfl_xor(gtot, 4, 64);
        float gG = __shfl_xor(gtot, 8, 64);
        float gO = __shfl_xor(gtot, 12, 64);

        if ((lane & 15) == 0) {
            float si = fast_sig(gI);
            float sf = fast_sig(gF);
            float so = fast_sig(gO);
            c_state = sf * c_state + si * fast_tanh(gG);
            float hv = so * fast_tanh(c_state);
            unsigned long long word =
                ((unsigned long long)(unsigned)(t + 1) << 32) |
                (unsigned long long)__float_as_uint(hv);
            __hip_atomic_store(h_own + (size_t)(t + 1) * HID + jg, word,
                               __ATOMIC_RELAXED, __HIP_MEMORY_SCOPE_AGENT);
            if (layer == 2) h2f[(size_t)t * HID + jg] = hv;
        }
    }
}

// ---------------- K3: logits = h2 @ w_lin^T + b_lin ----------------
#define BM 64
#define BN 64
#define BK 32
__global__ __launch_bounds__(256) void k3_logits(
    const float* __restrict__ A, const float* __restrict__ w_lin,
    const float* __restrict__ b_lin, float* __restrict__ out)
{
    int m0 = blockIdx.x * BM;
    int n0 = blockIdx.y * BN;
    int tid = threadIdx.x;
    __shared__ float As[BM][BK + 1];
    __shared__ float Bs[BN][BK + 1];
    float accv[4][4] = {};
    int tx = tid % 16, ty = tid / 16;

    for (int k0 = 0; k0 < HID; k0 += BK) {
        int row = tid / 4;
        int kq  = (tid % 4) * 8;
        {
            const float4* src = (const float4*)(A + (size_t)(m0 + row) * HID + k0 + kq);
            float4 v0 = src[0], v1 = src[1];
            As[row][kq + 0] = v0.x; As[row][kq + 1] = v0.y; As[row][kq + 2] = v0.z; As[row][kq + 3] = v0.w;
            As[row][kq + 4] = v1.x; As[row][kq + 5] = v1.y; As[row][kq + 6] = v1.z; As[row][kq + 7] = v1.w;
        }
        {
            int n = n0 + row;
            float4 v0 = make_float4(0.f, 0.f, 0.f, 0.f), v1 = v0;
            if (n < NSPK) {
                const float4* src = (const float4*)(w_lin + (size_t)n * HID + k0 + kq);
                v0 = src[0]; v1 = src[1];
            }
            Bs[row][kq + 0] = v0.x; Bs[row][kq + 1] = v0.y; Bs[row][kq + 2] = v0.z; Bs[row][kq + 3] = v0.w;
            Bs[row][kq + 4] = v1.x; Bs[row][kq + 5] = v1.y; Bs[row][kq + 6] = v1.z; Bs[row][kq + 7] = v1.w;
        }
        __syncthreads();
        #pragma unroll
        for (int kk = 0; kk < BK; kk++) {
            float a0 = As[ty * 4 + 0][kk], a1 = As[ty * 4 + 1][kk];
            float a2 = As[ty * 4 + 2][kk], a3 = As[ty * 4 + 3][kk];
            float b0 = Bs[tx * 4 + 0][kk], b1 = Bs[tx * 4 + 1][kk];
            float b2 = Bs[tx * 4 + 2][kk], b3 = Bs[tx * 4 + 3][kk];
            accv[0][0] += a0 * b0; accv[0][1] += a0 * b1; accv[0][2] += a0 * b2; accv[0][3] += a0 * b3;
            accv[1][0] += a1 * b0; accv[1][1] += a1 * b1; accv[1][2] += a1 * b2; accv[1][3] += a1 * b3;
            accv[2][0] += a2 * b0; accv[2][1] += a2 * b1; accv[2][2] += a2 * b2; accv[2][3] += a2 * b3;
            accv[3][0] += a3 * b0; accv[3][1] += a3 * b1; accv[3][2] += a3 * b2; accv[3][3] += a3 * b3;
        }
        __syncthreads();
    }
    #pragma unroll
    for (int i = 0; i < 4; i++) {
        int m = m0 + ty * 4 + i;
        #pragma unroll
        for (int j2 = 0; j2 < 4; j2++) {
            int n = n0 + tx * 4 + j2;
            if (n < NSPK) out[(size_t)m * NSPK + n] = accv[i][j2] + b_lin[n];
        }
    }
}

// ---------------- K4: in-place row-wise log_softmax ----------------
__global__ __launch_bounds__(256) void k4_logsoftmax(float* __restrict__ out)
{
    int t = blockIdx.x;
    float* row = out + (size_t)t * NSPK;
    int tid = threadIdx.x;
    __shared__ float red[8];
    float vals[5];
    float lmax = -1e30f;
    #pragma unroll
    for (int k = 0; k < 5; k++) {
        int n = tid + k * 256;
        vals[k] = (n < NSPK) ? row[n] : -1e30f;
        lmax = fmaxf(lmax, vals[k]);
    }
    #pragma unroll
    for (int m = 1; m < 64; m <<= 1) lmax = fmaxf(lmax, __shfl_xor(lmax, m, 64));
    int wave = tid >> 6;
    if ((tid & 63) == 0) red[wave] = lmax;
    __syncthreads();
    float gmax = fmaxf(fmaxf(red[0], red[1]), fmaxf(red[2], red[3]));
    float lsum = 0.f;
    #pragma unroll
    for (int k = 0; k < 5; k++) {
        int n = tid + k * 256;
        if (n < NSPK) lsum += __expf(vals[k] - gmax);
    }
    #pragma unroll
    for (int m = 1; m < 64; m <<= 1) lsum += __shfl_xor(lsum, m, 64);
    if ((tid & 63) == 0) red[4 + wave] = lsum;
    __syncthreads();
    float lse = logf(red[4] + red[5] + red[6] + red[7]) + gmax;
    #pragma unroll
    for (int k = 0; k < 5; k++) {
        int n = tid + k * 256;
        if (n < NSPK) row[n] = vals[k] - lse;
    }
}

extern "C" void kernel_launch(void* const* d_in, const int* in_sizes, int n_in,
                              void* d_out, int out_size, void* d_ws, size_t ws_size,
                              hipStream_t stream) {
    const float* x     = (const float*)d_in[0];
    const float* w_ih0 = (const float*)d_in[1];
    const float* w_hh0 = (const float*)d_in[2];
    const float* b_ih0 = (const float*)d_in[3];
    const float* b_hh0 = (const float*)d_in[4];
    const float* w_ih1 = (const float*)d_in[5];
    const float* w_hh1 = (const float*)d_in[6];
    const float* b_ih1 = (const float*)d_in[7];
    const float* b_hh1 = (const float*)d_in[8];
    const float* w_ih2 = (const float*)d_in[9];
    const float* w_hh2 = (const float*)d_in[10];
    const float* b_ih2 = (const float*)d_in[11];
    const float* b_hh2 = (const float*)d_in[12];
    const float* w_lin = (const float*)d_in[13];
    const float* b_lin = (const float*)d_in[14];

    unsigned long long* hbuf = (unsigned long long*)d_ws;
    float* xg  = (float*)((char*)d_ws + XG_OFF);
    float* h2f = (float*)((char*)d_ws + H2F_OFF);
    float* out = (float*)d_out;

    k0_init<<<1, 1024, 0, stream>>>(hbuf);
    k1_xproj<<<128, 256, 0, stream>>>(x, w_ih0, xg);
    k2_lstm<<<NBLOCKS, K2_THREADS, 0, stream>>>(
        w_ih1, w_hh0, b_ih0, b_hh0,
        w_hh1, b_ih1, b_hh1,
        w_ih2, w_hh2, b_ih2, b_hh2,
        xg, hbuf, h2f);
    k3_logits<<<dim3(16, 20), 256, 0, stream>>>(h2f, w_lin, b_lin, out);
    k4_logsoftmax<<<T_STEPS, 256, 0, stream>>>(out);
}